// Round 5
// baseline (97.888 us; speedup 1.0000x reference)
//
#include <hip/hip_runtime.h>
#include <stdint.h>

// DenseAttention: B=2, N=2048, D=1024, H=16, hd=64, causal tril, no softmax.
// Chunked linear-attention, all matmuls fp16 MFMA:
//   Qs = X @ (W*4096) / 16          (fp16 in LDS, = 256*Q_true)
//   U_c = X_c^T X_c (Gram, fp16), S_c = sum_{c'<c} U_{c'}  (fp16)
//   out_c = ( tril(Qs K^T) V + Qs S ) / 256
// 3 dispatches: prep_fused -> prefix16 -> qgemm_attn (GEMM + attention fused).
// qgemm_attn GEMM uses split-K waves (wr,wk): wave tile 64(rows)x64(cols) over
// half of K -> 8 ds_read_b128 per 262kFLOP = LDS/MFMA balanced (0.031 B/FLOP).
#define Bz 2
#define Nseq 2048
#define Dm 1024
#define Hh 16
#define NCHUNK 32
#define BKq 64

typedef _Float16 half_t;
typedef __attribute__((ext_vector_type(8))) _Float16 h8v;   // MFMA f16 A/B frag
typedef __attribute__((ext_vector_type(4))) _Float16 h4v;
typedef __attribute__((ext_vector_type(4))) float f4v;      // MFMA C/D frag

// async global->LDS, 16B/lane; LDS dest = wave-uniform base + lane*16 (linear).
#define GLDS(g, l)                                                        \
  __builtin_amdgcn_global_load_lds(                                       \
      (const __attribute__((address_space(1))) void*)(g),                 \
      (__attribute__((address_space(3))) void*)(l), 16, 0, 0)

// ---------------------------------------------------------------------------
// prep_fused:
//  blocks [0,1024): per (b,h,chunk): X fp32 -> Xf16; Gram U16 = X^T X (MFMA)
//  blocks [1024,1280): W fp32 [k][n] -> WT fp16 [n][k] * 4096
// ---------------------------------------------------------------------------
__global__ __launch_bounds__(256) void prep_fused(const float* __restrict__ X,
                                                  const float* __restrict__ W,
                                                  half_t* __restrict__ Xf,
                                                  half_t* __restrict__ U16,
                                                  half_t* __restrict__ WT) {
  __shared__ double smem_[2304];   // 18432 B, overlaid per branch
  int bx = blockIdx.x;
  int t = threadIdx.x;
  if (bx < 1024) {
    half_t(*xt)[72] = (half_t(*)[72])smem_;            // [m][d]
    half_t(*xtT)[72] = (half_t(*)[72])(smem_ + 1152);  // [d][m]
    int c = bx & 31, h = (bx >> 5) & 15, b = bx >> 9;
    int r = t >> 2, c16 = (t & 3) * 16;
    {
      const float* src = X + ((size_t)b * Nseq + c * 64 + r) * Dm + h * 64 + c16;
      half_t* dXf = Xf + ((size_t)b * Nseq + c * 64 + r) * Dm + h * 64 + c16;
      h8v v0, v1;
#pragma unroll
      for (int j = 0; j < 8; j++) { v0[j] = (half_t)src[j]; v1[j] = (half_t)src[8 + j]; }
      *(h8v*)&xt[r][c16] = v0;
      *(h8v*)&xt[r][c16 + 8] = v1;
      *(h8v*)&dXf[0] = v0;
      *(h8v*)&dXf[8] = v1;
    }
    __syncthreads();
    {
      int d = r, mg = c16;
      h8v v0, v1;
#pragma unroll
      for (int j = 0; j < 8; j++) { v0[j] = xt[mg + j][d]; v1[j] = xt[mg + 8 + j][d]; }
      *(h8v*)&xtT[d][mg] = v0;
      *(h8v*)&xtT[d][mg + 8] = v1;
    }
    __syncthreads();
    int wave = t >> 6, lane = t & 63;
    int lrow = lane & 15, lk = (lane >> 4) * 8;
    h8v a0 = *(h8v*)&xtT[wave * 16 + lrow][lk];
    h8v a1 = *(h8v*)&xtT[wave * 16 + lrow][32 + lk];
    f4v acc[4] = {};
#pragma unroll
    for (int j = 0; j < 4; j++) {
      acc[j] = __builtin_amdgcn_mfma_f32_16x16x32_f16(a0, *(h8v*)&xtT[j * 16 + lrow][lk], acc[j], 0, 0, 0);
      acc[j] = __builtin_amdgcn_mfma_f32_16x16x32_f16(a1, *(h8v*)&xtT[j * 16 + lrow][32 + lk], acc[j], 0, 0, 0);
    }
    half_t* ub = U16 + (size_t)bx * 4096;
#pragma unroll
    for (int j = 0; j < 4; j++)
#pragma unroll
      for (int v = 0; v < 4; v++)
        ub[(size_t)(wave * 16 + (lane >> 4) * 4 + v) * 64 + j * 16 + (lane & 15)] = (half_t)acc[j][v];
  } else {
    float(*tile)[65] = (float(*)[65])smem_;
    int bw = bx - 1024;
    int tk = bw >> 4, tn = bw & 15;
    int r = t >> 2, c0 = (t & 3) * 16;
    const float* src = W + (size_t)(tk * 64 + r) * Dm + tn * 64 + c0;
#pragma unroll
    for (int j = 0; j < 16; j++) tile[r][c0 + j] = src[j];
    __syncthreads();
    half_t* dst = WT + (size_t)(tn * 64 + r) * Dm + tk * 64 + c0;
    h8v v0, v1;
#pragma unroll
    for (int j = 0; j < 8; j++) {
      v0[j] = (half_t)(tile[c0 + j][r] * 4096.0f);
      v1[j] = (half_t)(tile[c0 + 8 + j][r] * 4096.0f);
    }
    *(h8v*)&dst[0] = v0;
    *(h8v*)&dst[8] = v1;
  }
}

// ---------------------------------------------------------------------------
// prefix16: exclusive prefix of U16 over chunks (fp32 accum) -> S16 fp16.
// ---------------------------------------------------------------------------
__global__ __launch_bounds__(256) void prefix16(const half_t* __restrict__ U16,
                                                half_t* __restrict__ S16) {
  int g = blockIdx.x * 256 + threadIdx.x;   // 32768 threads
  int bh = g >> 10, e4 = g & 1023;
  const half_t* u = U16 + (size_t)bh * NCHUNK * 4096 + e4 * 4;
  half_t* s = S16 + (size_t)bh * NCHUNK * 4096 + e4 * 4;
  float r0 = 0, r1 = 0, r2 = 0, r3 = 0;
  for (int c = 0; c < NCHUNK; c++) {
    h4v sv;
    sv[0] = (half_t)r0; sv[1] = (half_t)r1; sv[2] = (half_t)r2; sv[3] = (half_t)r3;
    *(h4v*)(s + (size_t)c * 4096) = sv;
    h4v uv = *(const h4v*)(u + (size_t)c * 4096);
    r0 += (float)uv[0]; r1 += (float)uv[1]; r2 += (float)uv[2]; r3 += (float)uv[3];
  }
}

// ---------------------------------------------------------------------------
// qgemm_attn: per block (bm,bn): 128x64 Q-tile GEMM (BK=64, dbuf GLDS,
// pre-swizzled source, split-K waves), LDS f32 reduction -> Qs fp16 in LDS,
// then attention for the 2 chunks those 128 rows form (head = bn).
// LDS map (55296 B total):
//   GEMM:    A dbuf [0,32768), B dbuf [32768,49152)
//   reduce:  f32 scratch [0,33792) (stride 66 floats, ~2-way = free)
//   park:    qs0 @36864, qs1 @46080   (64x72 f16 each)
//   chunks:  ks @0, vts @9216, ss @18432, pt @27648
// ---------------------------------------------------------------------------
__global__ __launch_bounds__(256) void qgemm_attn(const half_t* __restrict__ Xf,
                                                  const half_t* __restrict__ WT,
                                                  const half_t* __restrict__ S16,
                                                  float* __restrict__ out) {
  __shared__ __attribute__((aligned(16))) char smem[55296];
  int bid = blockIdx.x;
  int logical = (bid & 7) * 64 + (bid >> 3);   // bijective XCD swizzle (512=8*64)
  int bm = logical >> 4;   // 32 row panels (each = 2 chunks)
  int bn = logical & 15;   // head
  int t = threadIdx.x;
  int wave = t >> 6, lane = t & 63;
  int wr = wave >> 1, wk = wave & 1;   // split-K roles
  int lrow = lane & 15, g4 = lane >> 4;

  // ---------------- GEMM phase ----------------
  int srowA = wave * 32 + (lane >> 3);
  int srowB = wave * 16 + (lane >> 3);
  int scol = ((lane & 7) ^ (lane >> 3)) * 8;   // pre-swizzled source col (halves)
  const half_t* pA = Xf + (size_t)(bm * 128 + srowA) * Dm + scol;
  const half_t* pB = WT + (size_t)(bn * 64 + srowB) * Dm + scol;

  f4v acc[4][4] = {};   // wave tile: 64 rows (wr) x 64 cols, K-half wk
  {  // prologue: stage k=0 into buf0
    half_t* dA = (half_t*)(smem) + (wave * 32) * BKq;
    half_t* dB = (half_t*)(smem + 32768) + (wave * 16) * BKq;
#pragma unroll
    for (int q = 0; q < 4; q++) GLDS(pA + (size_t)q * 8 * Dm, dA + q * 8 * BKq);
#pragma unroll
    for (int q = 0; q < 2; q++) GLDS(pB + (size_t)q * 8 * Dm, dB + q * 8 * BKq);
  }
  __syncthreads();
  for (int it = 0; it < 16; ++it) {
    int cur = it & 1;
    if (it < 15) {   // stage next tile into the other buffer
      int k1 = (it + 1) * BKq;
      half_t* dA = (half_t*)(smem + (cur ^ 1) * 16384) + (wave * 32) * BKq;
      half_t* dB = (half_t*)(smem + 32768 + (cur ^ 1) * 8192) + (wave * 16) * BKq;
#pragma unroll
      for (int q = 0; q < 4; q++) GLDS(pA + (size_t)q * 8 * Dm + k1, dA + q * 8 * BKq);
#pragma unroll
      for (int q = 0; q < 2; q++) GLDS(pB + (size_t)q * 8 * Dm + k1, dB + q * 8 * BKq);
    }
    const char* cA = smem + cur * 16384;
    const char* cB = smem + 32768 + cur * 8192;
    uint koff = (uint)(wk * 64 + g4 * 16);
    h8v af[4], bf[4];
#pragma unroll
    for (int i = 0; i < 4; i++) {
      int rA = wr * 64 + i * 16 + lrow;
      af[i] = *(const h8v*)(cA + (uint)rA * 128 + (koff ^ (uint)((rA & 7) << 4)));
    }
#pragma unroll
    for (int j = 0; j < 4; j++) {
      int rB = j * 16 + lrow;
      bf[j] = *(const h8v*)(cB + (uint)rB * 128 + (koff ^ (uint)((rB & 7) << 4)));
    }
#pragma unroll
    for (int i = 0; i < 4; i++)
#pragma unroll
      for (int j = 0; j < 4; j++)
        acc[i][j] = __builtin_amdgcn_mfma_f32_16x16x32_f16(af[i], bf[j], acc[i][j], 0, 0, 0);
    __syncthreads();
  }

  // ---------------- split-K reduction + Qs park ----------------
  half_t(*qs0)[72] = (half_t(*)[72])(smem + 36864);
  half_t(*qs1)[72] = (half_t(*)[72])(smem + 46080);
  {
    float* scratch = (float*)smem;   // [128][66] f32
    if (wk) {
#pragma unroll
      for (int i = 0; i < 4; i++)
#pragma unroll
        for (int j = 0; j < 4; j++)
#pragma unroll
          for (int v = 0; v < 4; v++)
            scratch[(wr * 64 + i * 16 + (lane >> 4) * 4 + v) * 66 + j * 16 + (lane & 15)] =
                acc[i][j][v];
    }
    __syncthreads();
    if (!wk) {
      half_t(*qsw)[72] = wr ? qs1 : qs0;
#pragma unroll
      for (int i = 0; i < 4; i++)
#pragma unroll
        for (int j = 0; j < 4; j++)
#pragma unroll
          for (int v = 0; v < 4; v++) {
            int rr = i * 16 + (lane >> 4) * 4 + v, ccol = j * 16 + (lane & 15);
            float s = acc[i][j][v] + scratch[(wr * 64 + rr) * 66 + ccol];
            qsw[rr][ccol] = (half_t)(s * 0.0625f);
          }
    }
  }
  __syncthreads();

  // ---------------- attention epilogue (2 chunks) ----------------
  half_t(*ks)[72]  = (half_t(*)[72])(smem);
  half_t(*vts)[72] = (half_t(*)[72])(smem + 9216);
  half_t(*ss)[72]  = (half_t(*)[72])(smem + 18432);
  half_t(*pt)[72]  = (half_t(*)[72])(smem + 27648);
  int r = t >> 2, c16 = (t & 3) * 16;
  int lk = g4 * 8;
  int h = bn;
  for (int cc = 0; cc < 2; ++cc) {
    if (cc) __syncthreads();   // protect ks/ss/vts/pt reuse
    int gc = bm * 2 + cc;
    int b = gc >> 5, cl = gc & 31;
    {
      size_t rowoff = ((size_t)b * Nseq + cl * 64 + r) * Dm + h * 64 + c16;
      *(h8v*)&ks[r][c16]     = *(const h8v*)(Xf + rowoff);
      *(h8v*)&ks[r][c16 + 8] = *(const h8v*)(Xf + rowoff + 8);
      size_t soff = ((size_t)(b * Hh + h) * NCHUNK + cl) * 4096 + r * 64 + c16;
      *(h8v*)&ss[r][c16]     = *(const h8v*)(S16 + soff);
      *(h8v*)&ss[r][c16 + 8] = *(const h8v*)(S16 + soff + 8);
    }
    __syncthreads();
    half_t(*qsc)[72] = cc ? qs1 : qs0;
    h8v aq0 = *(h8v*)&qsc[wave * 16 + lrow][lk];
    h8v aq1 = *(h8v*)&qsc[wave * 16 + lrow][32 + lk];
    // P = Qs K^T   (wave owns rows wave*16..wave*16+15)
    f4v p[4] = {};
#pragma unroll
    for (int j = 0; j < 4; j++) {
      p[j] = __builtin_amdgcn_mfma_f32_16x16x32_f16(aq0, *(h8v*)&ks[j * 16 + lrow][lk], p[j], 0, 0, 0);
      p[j] = __builtin_amdgcn_mfma_f32_16x16x32_f16(aq1, *(h8v*)&ks[j * 16 + lrow][32 + lk], p[j], 0, 0, 0);
    }
    // in-LDS transpose ks -> vts (V^T operand; K tile == V tile)
    {
      int d = r, mg = c16;
      h8v v0, v1;
#pragma unroll
      for (int jj = 0; jj < 8; jj++) { v0[jj] = ks[mg + jj][d]; v1[jj] = ks[mg + 8 + jj][d]; }
      *(h8v*)&vts[d][mg] = v0;
      *(h8v*)&vts[d][mg + 8] = v1;
    }
    // tril mask, park P as fp16
    int orow = wave * 16 + (lane >> 4) * 4;
#pragma unroll
    for (int j = 0; j < 4; j++)
#pragma unroll
      for (int v = 0; v < 4; v++) {
        int rr = orow + v, mm = j * 16 + (lane & 15);
        pt[rr][mm] = (half_t)((mm <= rr) ? p[j][v] : 0.f);
      }
    __syncthreads();
    // O = P V + Qs S   (S symmetric -> row-major tile is its own B^T operand)
    h8v ap0 = *(h8v*)&pt[wave * 16 + lrow][lk];
    h8v ap1 = *(h8v*)&pt[wave * 16 + lrow][32 + lk];
    f4v o[4] = {};
#pragma unroll
    for (int j = 0; j < 4; j++) {
      o[j] = __builtin_amdgcn_mfma_f32_16x16x32_f16(ap0, *(h8v*)&vts[j * 16 + lrow][lk], o[j], 0, 0, 0);
      o[j] = __builtin_amdgcn_mfma_f32_16x16x32_f16(ap1, *(h8v*)&vts[j * 16 + lrow][32 + lk], o[j], 0, 0, 0);
      o[j] = __builtin_amdgcn_mfma_f32_16x16x32_f16(aq0, *(h8v*)&ss[j * 16 + lrow][lk], o[j], 0, 0, 0);
      o[j] = __builtin_amdgcn_mfma_f32_16x16x32_f16(aq1, *(h8v*)&ss[j * 16 + lrow][32 + lk], o[j], 0, 0, 0);
    }
    float* dst = out + ((size_t)b * Nseq + cl * 64) * Dm + h * 64;
#pragma unroll
    for (int j = 0; j < 4; j++)
#pragma unroll
      for (int v = 0; v < 4; v++)
        dst[(size_t)(orow + v) * Dm + j * 16 + (lane & 15)] = o[j][v] * 0.00390625f;
  }
}

// ---------------------------------------------------------------------------
extern "C" void kernel_launch(void* const* d_in, const int* in_sizes, int n_in,
                              void* d_out, int out_size, void* d_ws, size_t ws_size,
                              hipStream_t stream) {
  const float* X = (const float*)d_in[0];
  const float* W = (const float*)d_in[1];
  float* out = (float*)d_out;

  half_t* U16 = (half_t*)d_ws;                // 4194304 f16
  half_t* Xf = U16 + 4194304;                 // 4194304 f16
  half_t* S16 = Xf + 4194304;                 // 4194304 f16
  half_t* WT = S16 + 4194304;                 // 1048576 f16

  prep_fused<<<1280, 256, 0, stream>>>(X, W, Xf, U16, WT);
  prefix16<<<128, 256, 0, stream>>>(U16, S16);
  qgemm_attn<<<512, 256, 0, stream>>>(Xf, WT, S16, out);
}